// Round 4
// baseline (1183.265 us; speedup 1.0000x reference)
//
#include <hip/hip_runtime.h>
#include <math.h>

#define IN_F 512
#define OUTF 128
#define NEG_SLOPE 0.2f

// ---------------- proj1 geometry ----------------
#define PR 128        // rows per block
#define TK 32         // k-depth per tile
#define PITCH 36      // floats per LDS row: 16B-aligned, 4r-mod-32 bank spread (balanced)

// ---------------- prep: fold weights ----------------
// block 0: wfold[k][0..3]=W1@al1 (per head), [4..7]=W1@ar1, [8..11]=0.25*sum_d W1
// block 1: w2al[h] = W2[h,:]@al2, w2ar[h] = W2[h,:]@ar2
__global__ void k_prep(const float* __restrict__ fc1, const float* __restrict__ al1,
                       const float* __restrict__ ar1, const float* __restrict__ fc2,
                       const float* __restrict__ al2, const float* __restrict__ ar2,
                       float* __restrict__ wfold, float* __restrict__ w2al,
                       float* __restrict__ w2ar) {
  int t = threadIdx.x;
  if (blockIdx.x == 0) {
    int k = t;  // 512 threads
#pragma unroll
    for (int h = 0; h < 4; ++h) {
      float wl = 0.f, wr = 0.f, wb = 0.f;
#pragma unroll
      for (int j = 0; j < 4; ++j) {
        float wv = fc1[k * 16 + h * 4 + j];
        wl = fmaf(wv, al1[h * 4 + j], wl);
        wr = fmaf(wv, ar1[h * 4 + j], wr);
        wb += wv;
      }
      wfold[k * 12 + h] = wl;
      wfold[k * 12 + 4 + h] = wr;
      wfold[k * 12 + 8 + h] = 0.25f * wb;
    }
  } else if (t < 8) {
    int h = t >> 1;
    const float* a = (t & 1) ? ar2 : al2;
    float s = 0.f;
#pragma unroll 16
    for (int c = 0; c < OUTF; ++c) s += fc2[h * OUTF + c] * a[c];
    if (t & 1) w2ar[h] = s; else w2al[h] = s;
  }
}

// ---------------- zero accumulators ----------------
__global__ void k_zero4(float* __restrict__ p, int n4) {
  int i = blockIdx.x * blockDim.x + threadIdx.x;
  if (i < n4) *(float4*)&p[i * 4] = make_float4(0.f, 0.f, 0.f, 0.f);
}

// ---------------- layer 1 projection: 12 folded outputs ----------------
// rows: t&127; K halves: t>>7 (wave-uniform -> weights via s_load scalar path)
__global__ __launch_bounds__(256) void k_proj1(
    const float* __restrict__ x, const float* __restrict__ wf,
    float* __restrict__ el1, float* __restrict__ er1, float* __restrict__ hb1, int n)
{
  __shared__ float xs[PR * PITCH];
  const int t = threadIdx.x;
  const int r = t & 127;
  const int half = t >> 7;
  const int rowBase = blockIdx.x * PR;
  const int myRow = rowBase + r;
  float acc[12];
#pragma unroll
  for (int c = 0; c < 12; ++c) acc[c] = 0.f;

  float4 st[4];
#pragma unroll
  for (int i = 0; i < 4; ++i) {                 // prefetch tile 0
    int f4 = t + i * 256;
    int rr = f4 >> 3, kq = f4 & 7;
    int row = rowBase + rr;
    st[i] = (row < n) ? *(const float4*)&x[(size_t)row * IN_F + kq * 4]
                      : make_float4(0.f, 0.f, 0.f, 0.f);
  }

  for (int tile = 0; tile < IN_F / TK; ++tile) {
    __syncthreads();                            // xs consumed by previous compute
#pragma unroll
    for (int i = 0; i < 4; ++i) {
      int f4 = t + i * 256;
      int rr = f4 >> 3, kq = f4 & 7;
      *(float4*)&xs[rr * PITCH + kq * 4] = st[i];
    }
    if (tile + 1 < IN_F / TK) {
      int k0 = (tile + 1) * TK;
#pragma unroll
      for (int i = 0; i < 4; ++i) {
        int f4 = t + i * 256;
        int rr = f4 >> 3, kq = f4 & 7;
        int row = rowBase + rr;
        st[i] = (row < n) ? *(const float4*)&x[(size_t)row * IN_F + k0 + kq * 4]
                          : make_float4(0.f, 0.f, 0.f, 0.f);
      }
    }
    __syncthreads();
    const float* __restrict__ wk0 = wf + (size_t)(tile * TK + half * 16) * 12;
#pragma unroll
    for (int kq = 0; kq < 4; ++kq) {
      float4 xv = *(const float4*)&xs[r * PITCH + half * 16 + kq * 4];
      float xj[4] = {xv.x, xv.y, xv.z, xv.w};
#pragma unroll
      for (int j = 0; j < 4; ++j) {
        const float* __restrict__ wkk = wk0 + (kq * 4 + j) * 12;  // wave-uniform
#pragma unroll
        for (int c = 0; c < 12; ++c)
          acc[c] = fmaf(xj[j], wkk[c], acc[c]);
      }
    }
  }

  __syncthreads();                              // done reading xs; reuse for reduce
  if (half == 1) {
#pragma unroll
    for (int c = 0; c < 12; ++c) xs[r * 12 + c] = acc[c];
  }
  __syncthreads();
  if (half == 0 && myRow < n) {
#pragma unroll
    for (int c = 0; c < 12; ++c) acc[c] += xs[r * 12 + c];
    *(float4*)&el1[(size_t)myRow * 4] = make_float4(acc[0], acc[1], acc[2], acc[3]);
    *(float4*)&er1[(size_t)myRow * 4] = make_float4(acc[4], acc[5], acc[6], acc[7]);
    *(float4*)&hb1[(size_t)myRow * 4] = make_float4(acc[8], acc[9], acc[10], acc[11]);
  }
}

// ---------------- layer 1 edge-parallel aggregation (atomics) ----------------
__global__ void k_eagg1(const int* __restrict__ src, const int* __restrict__ dst,
                        const float* __restrict__ el1, const float* __restrict__ er1,
                        const float* __restrict__ hb1, float* __restrict__ den1,
                        float* __restrict__ num1, int e) {
  int i = blockIdx.x * blockDim.x + threadIdx.x;
  if (i >= e) return;
  int s = src[i], d = dst[i];
  float4 el = *(const float4*)&el1[(size_t)s * 4];
  float4 er = *(const float4*)&er1[(size_t)d * 4];
  float4 hb = *(const float4*)&hb1[(size_t)s * 4];
  float eh, w;
  eh = el.x + er.x; eh = (eh > 0.f) ? eh : NEG_SLOPE * eh; w = __expf(eh);
  atomicAdd(&den1[(size_t)d * 4 + 0], w); atomicAdd(&num1[(size_t)d * 4 + 0], w * hb.x);
  eh = el.y + er.y; eh = (eh > 0.f) ? eh : NEG_SLOPE * eh; w = __expf(eh);
  atomicAdd(&den1[(size_t)d * 4 + 1], w); atomicAdd(&num1[(size_t)d * 4 + 1], w * hb.y);
  eh = el.z + er.z; eh = (eh > 0.f) ? eh : NEG_SLOPE * eh; w = __expf(eh);
  atomicAdd(&den1[(size_t)d * 4 + 2], w); atomicAdd(&num1[(size_t)d * 4 + 2], w * hb.z);
  eh = el.w + er.w; eh = (eh > 0.f) ? eh : NEG_SLOPE * eh; w = __expf(eh);
  atomicAdd(&den1[(size_t)d * 4 + 3], w); atomicAdd(&num1[(size_t)d * 4 + 3], w * hb.w);
}

// ---------------- node update: mean+bias+relu, el2/er2 ----------------
__global__ void k_node1(const float* __restrict__ den1, const float* __restrict__ num1,
                        const float* __restrict__ bias1, const float* __restrict__ w2al,
                        const float* __restrict__ w2ar, float* __restrict__ h2in,
                        float* __restrict__ el2, float* __restrict__ er2, int n) {
  int nn = blockIdx.x * blockDim.x + threadIdx.x;
  if (nn >= n) return;
  float4 dn = *(const float4*)&den1[(size_t)nn * 4];
  float4 nm = *(const float4*)&num1[(size_t)nn * 4];
  float v[4];
  v[0] = (dn.x > 0.f) ? nm.x / dn.x : 0.f;
  v[1] = (dn.y > 0.f) ? nm.y / dn.y : 0.f;
  v[2] = (dn.z > 0.f) ? nm.z / dn.z : 0.f;
  v[3] = (dn.w > 0.f) ? nm.w / dn.w : 0.f;
  float pl = 0.f, pr = 0.f;
#pragma unroll
  for (int h = 0; h < 4; ++h) {
    float mb = 0.25f * (bias1[h*4] + bias1[h*4+1] + bias1[h*4+2] + bias1[h*4+3]);
    float vv = v[h] + mb;
    vv = (vv > 0.f) ? vv : 0.f;
    v[h] = vv;
    pl = fmaf(vv, w2al[h], pl);
    pr = fmaf(vv, w2ar[h], pr);
  }
  *(float4*)&h2in[(size_t)nn * 4] = make_float4(v[0], v[1], v[2], v[3]);
  el2[nn] = pl;
  er2[nn] = pr;
}

// ---------------- layer 2 edge-parallel aggregation (atomics) ----------------
__global__ void k_eagg2(const int* __restrict__ src, const int* __restrict__ dst,
                        const float* __restrict__ el2, const float* __restrict__ er2,
                        const float* __restrict__ h2in, float* __restrict__ g4,
                        float* __restrict__ den2, int e) {
  int i = blockIdx.x * blockDim.x + threadIdx.x;
  if (i >= e) return;
  int s = src[i], d = dst[i];
  float eh = el2[s] + er2[d];
  eh = (eh > 0.f) ? eh : NEG_SLOPE * eh;
  float w = __expf(eh);
  float4 hv = *(const float4*)&h2in[(size_t)s * 4];
  atomicAdd(&den2[d], w);
  atomicAdd(&g4[(size_t)d * 4 + 0], w * hv.x);
  atomicAdd(&g4[(size_t)d * 4 + 1], w * hv.y);
  atomicAdd(&g4[(size_t)d * 4 + 2], w * hv.z);
  atomicAdd(&g4[(size_t)d * 4 + 3], w * hv.w);
}

// ---------------- output projection: out = (g4/den2) @ W2 + bias2 ----------------
__global__ __launch_bounds__(256) void k_out(const float* __restrict__ g4,
                                             const float* __restrict__ den2,
                                             const float* __restrict__ w2,
                                             const float* __restrict__ bias2,
                                             float* __restrict__ out, int n) {
  int node = blockIdx.x * 4 + (threadIdx.x >> 6);
  if (node >= n) return;
  int lane = threadIdx.x & 63;
  float4 g = *(const float4*)&g4[(size_t)node * 4];   // wave-uniform broadcast
  float den = den2[node];
  float inv = (den > 0.f) ? 1.0f / den : 0.f;
  int c = lane * 2;
  float2 w0 = *(const float2*)&w2[c];
  float2 w1 = *(const float2*)&w2[OUTF + c];
  float2 wv2 = *(const float2*)&w2[2 * OUTF + c];
  float2 w3 = *(const float2*)&w2[3 * OUTF + c];
  float2 b = *(const float2*)&bias2[c];
  float2 o;
  o.x = (g.x * w0.x + g.y * w1.x + g.z * wv2.x + g.w * w3.x) * inv + b.x;
  o.y = (g.x * w0.y + g.y * w1.y + g.z * wv2.y + g.w * w3.y) * inv + b.y;
  *(float2*)&out[(size_t)node * OUTF + c] = o;
}

// ---------------- launch ----------------
extern "C" void kernel_launch(void* const* d_in, const int* in_sizes, int n_in,
                              void* d_out, int out_size, void* d_ws, size_t ws_size,
                              hipStream_t stream) {
  const float* nfeats = (const float*)d_in[0];
  const int*   srcp   = (const int*)d_in[2];
  const int*   dstp   = (const int*)d_in[3];
  const float* fc1    = (const float*)d_in[4];
  const float* al1    = (const float*)d_in[5];
  const float* ar1    = (const float*)d_in[6];
  const float* bias1  = (const float*)d_in[7];
  const float* fc2    = (const float*)d_in[8];
  const float* al2    = (const float*)d_in[9];
  const float* ar2    = (const float*)d_in[10];
  const float* bias2  = (const float*)d_in[11];

  const int N = in_sizes[0] / IN_F;     // 100000
  const int E = in_sizes[2];            // 1600000

  float* ws   = (float*)d_ws;
  float* el1  = ws;                          // 4N
  float* er1  = el1 + (size_t)4 * N;         // 4N
  float* hb1  = er1 + (size_t)4 * N;         // 4N
  float* h2in = hb1 + (size_t)4 * N;         // 4N
  float* el2  = h2in + (size_t)4 * N;        // N
  float* er2  = el2 + N;                     // N
  // zero-region (13N floats, contiguous):
  float* den1 = er2 + N;                     // 4N
  float* num1 = den1 + (size_t)4 * N;        // 4N
  float* g4   = num1 + (size_t)4 * N;        // 4N
  float* den2 = g4 + (size_t)4 * N;          // N
  float* wfold= den2 + N;                    // 512*12
  float* w2al = wfold + 512 * 12;            // 4
  float* w2ar = w2al + 4;                    // 4

  const int z4 = (13 * N) / 4;               // 13N divisible by 4

  k_zero4<<<(z4 + 255) / 256, 256, 0, stream>>>(den1, z4);
  k_prep<<<2, 512, 0, stream>>>(fc1, al1, ar1, fc2, al2, ar2, wfold, w2al, w2ar);
  k_proj1<<<(N + PR - 1) / PR, 256, 0, stream>>>(nfeats, wfold, el1, er1, hb1, N);
  k_eagg1<<<(E + 255) / 256, 256, 0, stream>>>(srcp, dstp, el1, er1, hb1,
                                               den1, num1, E);
  k_node1<<<(N + 255) / 256, 256, 0, stream>>>(den1, num1, bias1, w2al, w2ar,
                                               h2in, el2, er2, N);
  k_eagg2<<<(E + 255) / 256, 256, 0, stream>>>(srcp, dstp, el2, er2, h2in,
                                               g4, den2, E);
  k_out<<<(N + 3) / 4, 256, 0, stream>>>(g4, den2, fc2, bias2, (float*)d_out, N);
}

// Round 5
// 344.878 us; speedup vs baseline: 3.4310x; 3.4310x over previous
//
#include <hip/hip_runtime.h>
#include <math.h>

#define IN_F 512
#define OUTF 128
#define NEG_SLOPE 0.2f

// proj1 geometry
#define PR 128        // rows per block
#define TK 32         // k-depth per tile
#define PITCH 36      // floats per LDS row

// bucketing geometry
#define NPB 512               // nodes per bucket (dst >> 9)
#define EPB 4096              // edges per binning block
#define SRCMASK 0x1FFFF       // 17-bit src (N < 131072)

// ---------------- prep: fold weights + zero bucketTotal ----------------
__global__ void k_prep(const float* __restrict__ fc1, const float* __restrict__ al1,
                       const float* __restrict__ ar1, const float* __restrict__ fc2,
                       const float* __restrict__ al2, const float* __restrict__ ar2,
                       float* __restrict__ wfold, float* __restrict__ w2al,
                       float* __restrict__ w2ar, int* __restrict__ bucketTotal) {
  int t = threadIdx.x;
  if (blockIdx.x == 0) {
    int k = t;  // 512 threads
#pragma unroll
    for (int h = 0; h < 4; ++h) {
      float wl = 0.f, wr = 0.f, wb = 0.f;
#pragma unroll
      for (int j = 0; j < 4; ++j) {
        float wv = fc1[k * 16 + h * 4 + j];
        wl = fmaf(wv, al1[h * 4 + j], wl);
        wr = fmaf(wv, ar1[h * 4 + j], wr);
        wb += wv;
      }
      wfold[k * 12 + h] = wl;
      wfold[k * 12 + 4 + h] = wr;
      wfold[k * 12 + 8 + h] = 0.25f * wb;
    }
  } else {
    if (t < 8) {
      int h = t >> 1;
      const float* a = (t & 1) ? ar2 : al2;
      float s = 0.f;
#pragma unroll 16
      for (int c = 0; c < OUTF; ++c) s += fc2[h * OUTF + c] * a[c];
      if (t & 1) w2ar[h] = s; else w2al[h] = s;
    }
    if (t >= 8 && t < 264) bucketTotal[t - 8] = 0;
  }
}

// ---------------- layer 1 projection: 12 folded outputs ----------------
__global__ __launch_bounds__(256) void k_proj1(
    const float* __restrict__ x, const float* __restrict__ wf,
    float* __restrict__ el1, float* __restrict__ er1, float* __restrict__ hb1, int n)
{
  __shared__ float xs[PR * PITCH];
  const int t = threadIdx.x;
  const int r = t & 127;
  const int half = t >> 7;
  const int rowBase = blockIdx.x * PR;
  const int myRow = rowBase + r;
  float acc[12];
#pragma unroll
  for (int c = 0; c < 12; ++c) acc[c] = 0.f;

  float4 st[4];
#pragma unroll
  for (int i = 0; i < 4; ++i) {                 // prefetch tile 0
    int f4 = t + i * 256;
    int rr = f4 >> 3, kq = f4 & 7;
    int row = rowBase + rr;
    st[i] = (row < n) ? *(const float4*)&x[(size_t)row * IN_F + kq * 4]
                      : make_float4(0.f, 0.f, 0.f, 0.f);
  }

  for (int tile = 0; tile < IN_F / TK; ++tile) {
    __syncthreads();
#pragma unroll
    for (int i = 0; i < 4; ++i) {
      int f4 = t + i * 256;
      int rr = f4 >> 3, kq = f4 & 7;
      *(float4*)&xs[rr * PITCH + kq * 4] = st[i];
    }
    if (tile + 1 < IN_F / TK) {
      int k0 = (tile + 1) * TK;
#pragma unroll
      for (int i = 0; i < 4; ++i) {
        int f4 = t + i * 256;
        int rr = f4 >> 3, kq = f4 & 7;
        int row = rowBase + rr;
        st[i] = (row < n) ? *(const float4*)&x[(size_t)row * IN_F + k0 + kq * 4]
                          : make_float4(0.f, 0.f, 0.f, 0.f);
      }
    }
    __syncthreads();
    const float* __restrict__ wk0 = wf + (size_t)(tile * TK + half * 16) * 12;
#pragma unroll
    for (int kq = 0; kq < 4; ++kq) {
      float4 xv = *(const float4*)&xs[r * PITCH + half * 16 + kq * 4];
      float xj[4] = {xv.x, xv.y, xv.z, xv.w};
#pragma unroll
      for (int j = 0; j < 4; ++j) {
        const float* __restrict__ wkk = wk0 + (kq * 4 + j) * 12;  // wave-uniform
#pragma unroll
        for (int c = 0; c < 12; ++c)
          acc[c] = fmaf(xj[j], wkk[c], acc[c]);
      }
    }
  }

  __syncthreads();
  if (half == 1) {
#pragma unroll
    for (int c = 0; c < 12; ++c) xs[r * 12 + c] = acc[c];
  }
  __syncthreads();
  if (half == 0 && myRow < n) {
#pragma unroll
    for (int c = 0; c < 12; ++c) acc[c] += xs[r * 12 + c];
    *(float4*)&el1[(size_t)myRow * 4] = make_float4(acc[0], acc[1], acc[2], acc[3]);
    *(float4*)&er1[(size_t)myRow * 4] = make_float4(acc[4], acc[5], acc[6], acc[7]);
    *(float4*)&hb1[(size_t)myRow * 4] = make_float4(acc[8], acc[9], acc[10], acc[11]);
  }
}

// ---------------- bucket histogram ----------------
__global__ __launch_bounds__(256) void k_bhist(const int* __restrict__ dst,
                                               int* __restrict__ bucketTotal, int e) {
  __shared__ int hist[256];
  int t = threadIdx.x;
  hist[t] = 0;
  __syncthreads();
  int base = blockIdx.x * EPB;
#pragma unroll
  for (int i = 0; i < EPB / 256; ++i) {
    int idx = base + t + i * 256;
    if (idx < e) atomicAdd(&hist[dst[idx] >> 9], 1);
  }
  __syncthreads();
  if (hist[t] > 0) atomicAdd(&bucketTotal[t], hist[t]);
}

// ---------------- bucket scan (1 block) ----------------
__global__ __launch_bounds__(256) void k_bscan(const int* __restrict__ bucketTotal,
                                               int* __restrict__ bucketBase,
                                               int* __restrict__ bucketCursor,
                                               int nb, int e) {
  __shared__ int s[256];
  int t = threadIdx.x;
  int v = (t < nb) ? bucketTotal[t] : 0;
  s[t] = v;
  __syncthreads();
  for (int off = 1; off < 256; off <<= 1) {
    int u = (t >= off) ? s[t - off] : 0;
    __syncthreads();
    s[t] += u;
    __syncthreads();
  }
  int excl = s[t] - v;
  if (t < nb) { bucketBase[t] = excl; bucketCursor[t] = excl; }
  if (t == nb) bucketBase[t] = e;
}

// ---------------- binned scatter: block-aggregated reservation ----------------
__global__ __launch_bounds__(256) void k_bscat(const int* __restrict__ src,
                                               const int* __restrict__ dst,
                                               int* __restrict__ bucketCursor,
                                               unsigned* __restrict__ ep, int e) {
  __shared__ int hist[256];
  __shared__ int base[256];
  __shared__ int lcur[256];
  int t = threadIdx.x;
  hist[t] = 0;
  __syncthreads();
  int blockBase = blockIdx.x * EPB;
#pragma unroll
  for (int i = 0; i < EPB / 256; ++i) {
    int idx = blockBase + t + i * 256;
    if (idx < e) atomicAdd(&hist[dst[idx] >> 9], 1);
  }
  __syncthreads();
  if (hist[t] > 0) base[t] = atomicAdd(&bucketCursor[t], hist[t]);
  lcur[t] = 0;
  __syncthreads();
#pragma unroll
  for (int i = 0; i < EPB / 256; ++i) {
    int idx = blockBase + t + i * 256;
    if (idx < e) {
      int d = dst[idx];
      int b = d >> 9;
      int p = base[b] + atomicAdd(&lcur[b], 1);
      ep[p] = (unsigned)src[idx] | ((unsigned)(d & (NPB - 1)) << 17);
    }
  }
}

// ---------------- layer 1 bucket aggregation + node epilogue ----------------
__global__ __launch_bounds__(256) void k_bagg1(
    const unsigned* __restrict__ ep, const int* __restrict__ bucketBase,
    const float* __restrict__ el1, const float* __restrict__ er1,
    const float* __restrict__ hb1, const float* __restrict__ bias1,
    const float* __restrict__ w2al, const float* __restrict__ w2ar,
    float* __restrict__ h2in, float* __restrict__ el2, float* __restrict__ er2, int n)
{
  __shared__ float acc[NPB * 8];   // per node: den[4], num[4]
  __shared__ float ers[NPB * 4];
  int t = threadIdx.x;
  int b = blockIdx.x;
  int nodeBase = b * NPB;
  for (int i = t; i < NPB * 8; i += 256) acc[i] = 0.f;
  for (int i = t; i < NPB; i += 256) {
    int node = nodeBase + i;
    float4 v = (node < n) ? *(const float4*)&er1[(size_t)node * 4]
                          : make_float4(0.f, 0.f, 0.f, 0.f);
    *(float4*)&ers[i * 4] = v;
  }
  __syncthreads();
  int beg = bucketBase[b], end = bucketBase[b + 1];
  for (int j = beg + t; j < end; j += 256) {
    unsigned p = ep[j];
    int s = p & SRCMASK;
    int dl = p >> 17;
    float4 el = *(const float4*)&el1[(size_t)s * 4];
    float4 hb = *(const float4*)&hb1[(size_t)s * 4];
    float* a = &acc[dl * 8];
    float eh, w;
    eh = el.x + ers[dl*4+0]; eh = (eh > 0.f) ? eh : NEG_SLOPE * eh; w = __expf(eh);
    atomicAdd(&a[0], w); atomicAdd(&a[4], w * hb.x);
    eh = el.y + ers[dl*4+1]; eh = (eh > 0.f) ? eh : NEG_SLOPE * eh; w = __expf(eh);
    atomicAdd(&a[1], w); atomicAdd(&a[5], w * hb.y);
    eh = el.z + ers[dl*4+2]; eh = (eh > 0.f) ? eh : NEG_SLOPE * eh; w = __expf(eh);
    atomicAdd(&a[2], w); atomicAdd(&a[6], w * hb.z);
    eh = el.w + ers[dl*4+3]; eh = (eh > 0.f) ? eh : NEG_SLOPE * eh; w = __expf(eh);
    atomicAdd(&a[3], w); atomicAdd(&a[7], w * hb.w);
  }
  __syncthreads();
  float mb[4], wl[4], wr[4];
#pragma unroll
  for (int h = 0; h < 4; ++h) {
    mb[h] = 0.25f * (bias1[h*4] + bias1[h*4+1] + bias1[h*4+2] + bias1[h*4+3]);
    wl[h] = w2al[h]; wr[h] = w2ar[h];
  }
  for (int i = t; i < NPB; i += 256) {
    int node = nodeBase + i;
    if (node >= n) continue;
    float pl = 0.f, pr = 0.f, v[4];
#pragma unroll
    for (int h = 0; h < 4; ++h) {
      float den = acc[i * 8 + h];
      float num = acc[i * 8 + 4 + h];
      float vv = (den > 0.f) ? num / den : 0.f;
      vv += mb[h];
      vv = (vv > 0.f) ? vv : 0.f;
      v[h] = vv;
      pl = fmaf(vv, wl[h], pl);
      pr = fmaf(vv, wr[h], pr);
    }
    *(float4*)&h2in[(size_t)node * 4] = make_float4(v[0], v[1], v[2], v[3]);
    el2[node] = pl;
    er2[node] = pr;
  }
}

// ---------------- layer 2 bucket aggregation + fused output projection ----------------
__global__ __launch_bounds__(256) void k_bagg2(
    const unsigned* __restrict__ ep, const int* __restrict__ bucketBase,
    const float* __restrict__ el2, const float* __restrict__ er2,
    const float* __restrict__ h2in, const float* __restrict__ w2,
    const float* __restrict__ bias2, float* __restrict__ out, int n)
{
  __shared__ float acc[NPB * 5];   // per node: den, g[4]
  __shared__ float ers2[NPB];
  __shared__ float w2s[4 * OUTF];
  __shared__ float b2s[OUTF];
  int t = threadIdx.x;
  int b = blockIdx.x;
  int nodeBase = b * NPB;
  for (int i = t; i < NPB * 5; i += 256) acc[i] = 0.f;
  for (int i = t; i < NPB; i += 256) {
    int node = nodeBase + i;
    ers2[i] = (node < n) ? er2[node] : 0.f;
  }
  for (int i = t; i < 4 * OUTF; i += 256) w2s[i] = w2[i];
  if (t < OUTF) b2s[t] = bias2[t];
  __syncthreads();
  int beg = bucketBase[b], end = bucketBase[b + 1];
  for (int j = beg + t; j < end; j += 256) {
    unsigned p = ep[j];
    int s = p & SRCMASK;
    int dl = p >> 17;
    float eh = el2[s] + ers2[dl];
    eh = (eh > 0.f) ? eh : NEG_SLOPE * eh;
    float w = __expf(eh);
    float4 hv = *(const float4*)&h2in[(size_t)s * 4];
    float* a = &acc[dl * 5];
    atomicAdd(&a[0], w);
    atomicAdd(&a[1], w * hv.x);
    atomicAdd(&a[2], w * hv.y);
    atomicAdd(&a[3], w * hv.z);
    atomicAdd(&a[4], w * hv.w);
  }
  __syncthreads();
  for (int idx = t; idx < NPB * (OUTF / 2); idx += 256) {
    int i = idx >> 6;
    int node = nodeBase + i;
    if (node >= n) continue;
    int c = (idx & 63) * 2;
    float den = acc[i * 5];
    float inv = (den > 0.f) ? 1.0f / den : 0.f;
    float gx = acc[i*5+1] * inv, gy = acc[i*5+2] * inv;
    float gz = acc[i*5+3] * inv, gw = acc[i*5+4] * inv;
    float2 o;
    o.x = gx*w2s[c]   + gy*w2s[OUTF+c]   + gz*w2s[2*OUTF+c]   + gw*w2s[3*OUTF+c]   + b2s[c];
    o.y = gx*w2s[c+1] + gy*w2s[OUTF+c+1] + gz*w2s[2*OUTF+c+1] + gw*w2s[3*OUTF+c+1] + b2s[c+1];
    *(float2*)&out[(size_t)node * OUTF + c] = o;
  }
}

// ---------------- launch ----------------
extern "C" void kernel_launch(void* const* d_in, const int* in_sizes, int n_in,
                              void* d_out, int out_size, void* d_ws, size_t ws_size,
                              hipStream_t stream) {
  const float* nfeats = (const float*)d_in[0];
  const int*   srcp   = (const int*)d_in[2];
  const int*   dstp   = (const int*)d_in[3];
  const float* fc1    = (const float*)d_in[4];
  const float* al1    = (const float*)d_in[5];
  const float* ar1    = (const float*)d_in[6];
  const float* bias1  = (const float*)d_in[7];
  const float* fc2    = (const float*)d_in[8];
  const float* al2    = (const float*)d_in[9];
  const float* ar2    = (const float*)d_in[10];
  const float* bias2  = (const float*)d_in[11];

  const int N = in_sizes[0] / IN_F;     // 100000
  const int E = in_sizes[2];            // 1600000
  const int NB = (N + NPB - 1) / NPB;   // 196

  float* ws   = (float*)d_ws;
  float* el1  = ws;                          // 4N
  float* er1  = el1 + (size_t)4 * N;         // 4N
  float* hb1  = er1 + (size_t)4 * N;         // 4N
  float* h2in = hb1 + (size_t)4 * N;         // 4N
  float* el2  = h2in + (size_t)4 * N;        // N
  float* er2  = el2 + N;                     // N
  float* wfold= er2 + N;                     // 512*12
  float* w2al = wfold + 512 * 12;            // 4
  float* w2ar = w2al + 4;                    // 4
  int* bucketTotal  = (int*)(w2ar + 4);      // 256
  int* bucketBase   = bucketTotal + 256;     // 257
  int* bucketCursor = bucketBase + 257;      // 256
  unsigned* ep      = (unsigned*)(bucketCursor + 256);  // E

  const int binBlocks = (E + EPB - 1) / EPB; // 391

  k_prep<<<2, 512, 0, stream>>>(fc1, al1, ar1, fc2, al2, ar2,
                                wfold, w2al, w2ar, bucketTotal);
  k_bhist<<<binBlocks, 256, 0, stream>>>(dstp, bucketTotal, E);
  k_proj1<<<(N + PR - 1) / PR, 256, 0, stream>>>(nfeats, wfold, el1, er1, hb1, N);
  k_bscan<<<1, 256, 0, stream>>>(bucketTotal, bucketBase, bucketCursor, NB, E);
  k_bscat<<<binBlocks, 256, 0, stream>>>(srcp, dstp, bucketCursor, ep, E);
  k_bagg1<<<NB, 256, 0, stream>>>(ep, bucketBase, el1, er1, hb1, bias1,
                                  w2al, w2ar, h2in, el2, er2, N);
  k_bagg2<<<NB, 256, 0, stream>>>(ep, bucketBase, el2, er2, h2in,
                                  fc2, bias2, (float*)d_out, N);
}

// Round 6
// 269.534 us; speedup vs baseline: 4.3900x; 1.2795x over previous
//
#include <hip/hip_runtime.h>
#include <math.h>

#define IN_F 512
#define OUTF 128
#define NEG_SLOPE 0.2f

// proj1 geometry
#define KS 2          // K split across blocks (grid.y)
#define PR 256        // rows per block (1 per thread)
#define TK 32         // k-depth per tile
#define PITCH 36      // floats per LDS row (measured 0 bank conflicts)
#define TILES ((IN_F / KS) / TK)   // 8

// bucketing geometry
#define NPB 512               // nodes per bucket (dst >> 9)
#define NPSUB 128             // nodes per aggregation sub-block
#define EPB 8192              // edges per binning block
#define SRCMASK 0x1FFFF       // 17-bit src (N < 131072)

// ---------------- prep: fold weights + zero bucketTotal ----------------
__global__ void k_prep(const float* __restrict__ fc1, const float* __restrict__ al1,
                       const float* __restrict__ ar1, const float* __restrict__ fc2,
                       const float* __restrict__ al2, const float* __restrict__ ar2,
                       float* __restrict__ wfold, float* __restrict__ w2al,
                       float* __restrict__ w2ar, int* __restrict__ bucketTotal) {
  int t = threadIdx.x;
  if (blockIdx.x == 0) {
    int k = t;  // 512 threads
#pragma unroll
    for (int h = 0; h < 4; ++h) {
      float wl = 0.f, wr = 0.f, wb = 0.f;
#pragma unroll
      for (int j = 0; j < 4; ++j) {
        float wv = fc1[k * 16 + h * 4 + j];
        wl = fmaf(wv, al1[h * 4 + j], wl);
        wr = fmaf(wv, ar1[h * 4 + j], wr);
        wb += wv;
      }
      wfold[k * 12 + h] = wl;
      wfold[k * 12 + 4 + h] = wr;
      wfold[k * 12 + 8 + h] = 0.25f * wb;
    }
  } else {
    if (t < 8) {
      int h = t >> 1;
      const float* a = (t & 1) ? ar2 : al2;
      float s = 0.f;
#pragma unroll 16
      for (int c = 0; c < OUTF; ++c) s += fc2[h * OUTF + c] * a[c];
      if (t & 1) w2ar[h] = s; else w2al[h] = s;
    }
    if (t < 256) bucketTotal[t] = 0;
  }
}

// ---------------- layer 1 projection: 12 folded outputs, K split via grid.y ----------------
// Weight addresses depend only on blockIdx.y + loop counters -> wave-uniform -> s_load.
__global__ __launch_bounds__(256) void k_proj1(
    const float* __restrict__ x, const float* __restrict__ wf,
    float* __restrict__ part, int n)
{
  __shared__ float xs[PR * PITCH];
  const int t = threadIdx.x;
  const int rowBase = blockIdx.x * PR;
  const int kBase = blockIdx.y * (IN_F / KS);
  const int myRow = rowBase + t;
  float acc[12];
#pragma unroll
  for (int c = 0; c < 12; ++c) acc[c] = 0.f;

  float4 st[8];
#pragma unroll
  for (int i = 0; i < 8; ++i) {                 // prefetch tile 0
    int f4 = t + i * 256;
    int rr = f4 >> 3, kq4 = (f4 & 7) << 2;
    int row = rowBase + rr;
    st[i] = (row < n) ? *(const float4*)&x[(size_t)row * IN_F + kBase + kq4]
                      : make_float4(0.f, 0.f, 0.f, 0.f);
  }

  for (int tile = 0; tile < TILES; ++tile) {
    __syncthreads();                            // xs consumed by previous compute
#pragma unroll
    for (int i = 0; i < 8; ++i) {
      int f4 = t + i * 256;
      int rr = f4 >> 3, kq4 = (f4 & 7) << 2;
      *(float4*)&xs[rr * PITCH + kq4] = st[i];
    }
    if (tile + 1 < TILES) {
      int k0 = kBase + (tile + 1) * TK;
#pragma unroll
      for (int i = 0; i < 8; ++i) {
        int f4 = t + i * 256;
        int rr = f4 >> 3, kq4 = (f4 & 7) << 2;
        int row = rowBase + rr;
        st[i] = (row < n) ? *(const float4*)&x[(size_t)row * IN_F + k0 + kq4]
                          : make_float4(0.f, 0.f, 0.f, 0.f);
      }
    }
    __syncthreads();
    const float* __restrict__ wk0 = wf + (size_t)(kBase + tile * TK) * 12;
#pragma unroll
    for (int kq = 0; kq < 8; ++kq) {
      float4 xv = *(const float4*)&xs[t * PITCH + kq * 4];
      float xj[4] = {xv.x, xv.y, xv.z, xv.w};
#pragma unroll
      for (int j = 0; j < 4; ++j) {
        const float* __restrict__ wkk = wk0 + (kq * 4 + j) * 12;  // uniform -> s_load
#pragma unroll
        for (int c = 0; c < 12; ++c)
          acc[c] = fmaf(xj[j], wkk[c], acc[c]);
      }
    }
  }

  if (myRow < n) {
    float* p = part + ((size_t)blockIdx.y * n + myRow) * 12;
    *(float4*)&p[0] = make_float4(acc[0], acc[1], acc[2], acc[3]);
    *(float4*)&p[4] = make_float4(acc[4], acc[5], acc[6], acc[7]);
    *(float4*)&p[8] = make_float4(acc[8], acc[9], acc[10], acc[11]);
  }
}

// ---------------- combine K-split partials ----------------
__global__ void k_comb(const float* __restrict__ part, float* __restrict__ el1,
                       float* __restrict__ er1, float* __restrict__ hb1, int n) {
  int nn = blockIdx.x * blockDim.x + threadIdx.x;
  if (nn >= n) return;
  const float* p0 = part + (size_t)nn * 12;
  const float* p1 = part + ((size_t)n + nn) * 12;
  float4 a0 = *(const float4*)&p0[0], b0 = *(const float4*)&p1[0];
  float4 a1 = *(const float4*)&p0[4], b1 = *(const float4*)&p1[4];
  float4 a2 = *(const float4*)&p0[8], b2 = *(const float4*)&p1[8];
  *(float4*)&el1[(size_t)nn * 4] = make_float4(a0.x+b0.x, a0.y+b0.y, a0.z+b0.z, a0.w+b0.w);
  *(float4*)&er1[(size_t)nn * 4] = make_float4(a1.x+b1.x, a1.y+b1.y, a1.z+b1.z, a1.w+b1.w);
  *(float4*)&hb1[(size_t)nn * 4] = make_float4(a2.x+b2.x, a2.y+b2.y, a2.z+b2.z, a2.w+b2.w);
}

// ---------------- bucket histogram ----------------
__global__ __launch_bounds__(256) void k_bhist(const int* __restrict__ dst,
                                               int* __restrict__ bucketTotal, int e) {
  __shared__ int hist[256];
  int t = threadIdx.x;
  hist[t] = 0;
  __syncthreads();
  int base = blockIdx.x * EPB;
#pragma unroll
  for (int i = 0; i < EPB / 256; ++i) {
    int idx = base + t + i * 256;
    if (idx < e) atomicAdd(&hist[dst[idx] >> 9], 1);
  }
  __syncthreads();
  if (hist[t] > 0) atomicAdd(&bucketTotal[t], hist[t]);
}

// ---------------- bucket scan (1 block) ----------------
__global__ __launch_bounds__(256) void k_bscan(const int* __restrict__ bucketTotal,
                                               int* __restrict__ bucketBase,
                                               int* __restrict__ bucketCursor,
                                               int nb, int e) {
  __shared__ int s[256];
  int t = threadIdx.x;
  int v = (t < nb) ? bucketTotal[t] : 0;
  s[t] = v;
  __syncthreads();
  for (int off = 1; off < 256; off <<= 1) {
    int u = (t >= off) ? s[t - off] : 0;
    __syncthreads();
    s[t] += u;
    __syncthreads();
  }
  int excl = s[t] - v;
  if (t < nb) { bucketBase[t] = excl; bucketCursor[t] = excl; }
  if (t == nb) bucketBase[t] = e;
}

// ---------------- binned scatter: block-aggregated reservation ----------------
__global__ __launch_bounds__(256) void k_bscat(const int* __restrict__ src,
                                               const int* __restrict__ dst,
                                               int* __restrict__ bucketCursor,
                                               unsigned* __restrict__ ep, int e) {
  __shared__ int hist[256];
  __shared__ int base[256];
  __shared__ int lcur[256];
  int t = threadIdx.x;
  hist[t] = 0;
  __syncthreads();
  int blockBase = blockIdx.x * EPB;
#pragma unroll
  for (int i = 0; i < EPB / 256; ++i) {
    int idx = blockBase + t + i * 256;
    if (idx < e) atomicAdd(&hist[dst[idx] >> 9], 1);
  }
  __syncthreads();
  if (hist[t] > 0) base[t] = atomicAdd(&bucketCursor[t], hist[t]);
  lcur[t] = 0;
  __syncthreads();
#pragma unroll
  for (int i = 0; i < EPB / 256; ++i) {
    int idx = blockBase + t + i * 256;
    if (idx < e) {
      int d = dst[idx];
      int b = d >> 9;
      int p = base[b] + atomicAdd(&lcur[b], 1);
      ep[p] = (unsigned)src[idx] | ((unsigned)(d & (NPB - 1)) << 17);
    }
  }
}

// ---------------- layer 1 bucket aggregation + node epilogue (quarter-bucket blocks) ----------------
__global__ __launch_bounds__(256) void k_bagg1(
    const unsigned* __restrict__ ep, const int* __restrict__ bucketBase,
    const float* __restrict__ el1, const float* __restrict__ er1,
    const float* __restrict__ hb1, const float* __restrict__ bias1,
    const float* __restrict__ w2al, const float* __restrict__ w2ar,
    float* __restrict__ h2in, float* __restrict__ el2, float* __restrict__ er2, int n)
{
  __shared__ float acc[NPSUB * 8];   // per node: den[4], num[4]
  __shared__ float ers[NPSUB * 4];
  int t = threadIdx.x;
  int b = blockIdx.x;
  int sub = blockIdx.y;
  int nodeBase = b * NPB + sub * NPSUB;
  for (int i = t; i < NPSUB * 8; i += 256) acc[i] = 0.f;
  for (int i = t; i < NPSUB; i += 256) {
    int node = nodeBase + i;
    float4 v = (node < n) ? *(const float4*)&er1[(size_t)node * 4]
                          : make_float4(0.f, 0.f, 0.f, 0.f);
    *(float4*)&ers[i * 4] = v;
  }
  __syncthreads();
  int beg = bucketBase[b], end = bucketBase[b + 1];
  for (int j = beg + t; j < end; j += 256) {
    unsigned p = ep[j];
    int dl = p >> 17;
    if ((dl >> 7) != sub) continue;
    int s = p & SRCMASK;
    int dq = dl & (NPSUB - 1);
    float4 el = *(const float4*)&el1[(size_t)s * 4];
    float4 hb = *(const float4*)&hb1[(size_t)s * 4];
    float* a = &acc[dq * 8];
    float eh, w;
    eh = el.x + ers[dq*4+0]; eh = (eh > 0.f) ? eh : NEG_SLOPE * eh; w = __expf(eh);
    atomicAdd(&a[0], w); atomicAdd(&a[4], w * hb.x);
    eh = el.y + ers[dq*4+1]; eh = (eh > 0.f) ? eh : NEG_SLOPE * eh; w = __expf(eh);
    atomicAdd(&a[1], w); atomicAdd(&a[5], w * hb.y);
    eh = el.z + ers[dq*4+2]; eh = (eh > 0.f) ? eh : NEG_SLOPE * eh; w = __expf(eh);
    atomicAdd(&a[2], w); atomicAdd(&a[6], w * hb.z);
    eh = el.w + ers[dq*4+3]; eh = (eh > 0.f) ? eh : NEG_SLOPE * eh; w = __expf(eh);
    atomicAdd(&a[3], w); atomicAdd(&a[7], w * hb.w);
  }
  __syncthreads();
  float mb[4], wl[4], wr[4];
#pragma unroll
  for (int h = 0; h < 4; ++h) {
    mb[h] = 0.25f * (bias1[h*4] + bias1[h*4+1] + bias1[h*4+2] + bias1[h*4+3]);
    wl[h] = w2al[h]; wr[h] = w2ar[h];
  }
  for (int i = t; i < NPSUB; i += 256) {
    int node = nodeBase + i;
    if (node >= n) continue;
    float pl = 0.f, pr = 0.f, v[4];
#pragma unroll
    for (int h = 0; h < 4; ++h) {
      float den = acc[i * 8 + h];
      float num = acc[i * 8 + 4 + h];
      float vv = (den > 0.f) ? num / den : 0.f;
      vv += mb[h];
      vv = (vv > 0.f) ? vv : 0.f;
      v[h] = vv;
      pl = fmaf(vv, wl[h], pl);
      pr = fmaf(vv, wr[h], pr);
    }
    *(float4*)&h2in[(size_t)node * 4] = make_float4(v[0], v[1], v[2], v[3]);
    el2[node] = pl;
    er2[node] = pr;
  }
}

// ---------------- layer 2 bucket aggregation + fused output projection ----------------
__global__ __launch_bounds__(256) void k_bagg2(
    const unsigned* __restrict__ ep, const int* __restrict__ bucketBase,
    const float* __restrict__ el2, const float* __restrict__ er2,
    const float* __restrict__ h2in, const float* __restrict__ w2,
    const float* __restrict__ bias2, float* __restrict__ out, int n)
{
  __shared__ float acc[NPSUB * 5];   // per node: den, g[4]
  __shared__ float ers2[NPSUB];
  __shared__ float w2s[4 * OUTF];
  __shared__ float b2s[OUTF];
  int t = threadIdx.x;
  int b = blockIdx.x;
  int sub = blockIdx.y;
  int nodeBase = b * NPB + sub * NPSUB;
  for (int i = t; i < NPSUB * 5; i += 256) acc[i] = 0.f;
  for (int i = t; i < NPSUB; i += 256) {
    int node = nodeBase + i;
    ers2[i] = (node < n) ? er2[node] : 0.f;
  }
  for (int i = t; i < 4 * OUTF; i += 256) w2s[i] = w2[i];
  if (t < OUTF) b2s[t] = bias2[t];
  __syncthreads();
  int beg = bucketBase[b], end = bucketBase[b + 1];
  for (int j = beg + t; j < end; j += 256) {
    unsigned p = ep[j];
    int dl = p >> 17;
    if ((dl >> 7) != sub) continue;
    int s = p & SRCMASK;
    int dq = dl & (NPSUB - 1);
    float eh = el2[s] + ers2[dq];
    eh = (eh > 0.f) ? eh : NEG_SLOPE * eh;
    float w = __expf(eh);
    float4 hv = *(const float4*)&h2in[(size_t)s * 4];
    float* a = &acc[dq * 5];
    atomicAdd(&a[0], w);
    atomicAdd(&a[1], w * hv.x);
    atomicAdd(&a[2], w * hv.y);
    atomicAdd(&a[3], w * hv.z);
    atomicAdd(&a[4], w * hv.w);
  }
  __syncthreads();
  for (int idx = t; idx < NPSUB * (OUTF / 2); idx += 256) {
    int i = idx >> 6;
    int node = nodeBase + i;
    if (node >= n) continue;
    int c = (idx & 63) * 2;
    float den = acc[i * 5];
    float inv = (den > 0.f) ? 1.0f / den : 0.f;
    float gx = acc[i*5+1] * inv, gy = acc[i*5+2] * inv;
    float gz = acc[i*5+3] * inv, gw = acc[i*5+4] * inv;
    float2 o;
    o.x = gx*w2s[c]   + gy*w2s[OUTF+c]   + gz*w2s[2*OUTF+c]   + gw*w2s[3*OUTF+c]   + b2s[c];
    o.y = gx*w2s[c+1] + gy*w2s[OUTF+c+1] + gz*w2s[2*OUTF+c+1] + gw*w2s[3*OUTF+c+1] + b2s[c+1];
    *(float2*)&out[(size_t)node * OUTF + c] = o;
  }
}

// ---------------- launch ----------------
extern "C" void kernel_launch(void* const* d_in, const int* in_sizes, int n_in,
                              void* d_out, int out_size, void* d_ws, size_t ws_size,
                              hipStream_t stream) {
  const float* nfeats = (const float*)d_in[0];
  const int*   srcp   = (const int*)d_in[2];
  const int*   dstp   = (const int*)d_in[3];
  const float* fc1    = (const float*)d_in[4];
  const float* al1    = (const float*)d_in[5];
  const float* ar1    = (const float*)d_in[6];
  const float* bias1  = (const float*)d_in[7];
  const float* fc2    = (const float*)d_in[8];
  const float* al2    = (const float*)d_in[9];
  const float* ar2    = (const float*)d_in[10];
  const float* bias2  = (const float*)d_in[11];

  const int N = in_sizes[0] / IN_F;     // 100000
  const int E = in_sizes[2];            // 1600000
  const int NB = (N + NPB - 1) / NPB;   // 196

  float* ws   = (float*)d_ws;
  float* part = ws;                          // KS * 12N
  float* el1  = part + (size_t)KS * 12 * N;  // 4N
  float* er1  = el1 + (size_t)4 * N;         // 4N
  float* hb1  = er1 + (size_t)4 * N;         // 4N
  float* h2in = hb1 + (size_t)4 * N;         // 4N
  float* el2  = h2in + (size_t)4 * N;        // N
  float* er2  = el2 + N;                     // N
  float* wfold= er2 + N;                     // 512*12
  float* w2al = wfold + 512 * 12;            // 4
  float* w2ar = w2al + 4;                    // 4
  int* bucketTotal  = (int*)(w2ar + 4);      // 256
  int* bucketBase   = bucketTotal + 256;     // 257
  int* bucketCursor = bucketBase + 257;      // 256
  unsigned* ep      = (unsigned*)(bucketCursor + 256);  // E

  const int binBlocks = (E + EPB - 1) / EPB; // 196
  const int projBlocks = (N + PR - 1) / PR;  // 391

  k_prep<<<2, 512, 0, stream>>>(fc1, al1, ar1, fc2, al2, ar2,
                                wfold, w2al, w2ar, bucketTotal);
  k_bhist<<<binBlocks, 256, 0, stream>>>(dstp, bucketTotal, E);
  k_proj1<<<dim3(projBlocks, KS), 256, 0, stream>>>(nfeats, wfold, part, N);
  k_bscan<<<1, 256, 0, stream>>>(bucketTotal, bucketBase, bucketCursor, NB, E);
  k_bscat<<<binBlocks, 256, 0, stream>>>(srcp, dstp, bucketCursor, ep, E);
  k_comb<<<(N + 255) / 256, 256, 0, stream>>>(part, el1, er1, hb1, N);
  k_bagg1<<<dim3(NB, 4), 256, 0, stream>>>(ep, bucketBase, el1, er1, hb1, bias1,
                                           w2al, w2ar, h2in, el2, er2, N);
  k_bagg2<<<dim3(NB, 4), 256, 0, stream>>>(ep, bucketBase, el2, er2, h2in,
                                           fc2, bias2, (float*)d_out, N);
}